// Round 1
// baseline (1005.477 us; speedup 1.0000x reference)
//
#include <hip/hip_runtime.h>
#include <hip/hip_bf16.h>
#include <math.h>

#define N_NODES 50000
#define N_EDGES 800000
#define NH 4
#define ND 64
#define NF 256   // NH*ND = feature width everywhere (IN=256 too)
#define NC 16
#define NEG_SLOPE 0.2f

__device__ __forceinline__ float elu_f(float x) {
    return x > 0.f ? x : (__expf(x) - 1.f);
}

// ---------------- GEMM: C[M,256] = A[M,256] @ B[256,256], f32 ----------------
// 64x64 tile, BK=16, 256 threads, 4x4 micro-tile per thread.
__global__ __launch_bounds__(256) void gemm256(const float* __restrict__ A,
                                               const float* __restrict__ B,
                                               float* __restrict__ C, int M) {
    __shared__ __align__(16) float As[64][20];  // pad 20: float4-write ok, 2-way read conflict (free)
    __shared__ __align__(16) float Bs[16][64];
    const int tid = threadIdx.x;
    const int tx = tid & 15, ty = tid >> 4;
    const int m0 = blockIdx.x * 64;
    const int n0 = blockIdx.y * 64;
    float acc[4][4] = {};
    for (int k0 = 0; k0 < 256; k0 += 16) {
        {   // A tile: 64 rows x 16 cols
            int r = tid >> 2, c = (tid & 3) * 4;
            float4 v = make_float4(0.f, 0.f, 0.f, 0.f);
            int row = m0 + r;
            if (row < M) v = *(const float4*)(A + row * 256 + k0 + c);
            *(float4*)(&As[r][c]) = v;
        }
        {   // B tile: 16 rows x 64 cols
            int r = tid >> 4, c = (tid & 15) * 4;
            float4 v = *(const float4*)(B + (k0 + r) * 256 + n0 + c);
            *(float4*)(&Bs[r][c]) = v;
        }
        __syncthreads();
        #pragma unroll
        for (int kk = 0; kk < 16; ++kk) {
            float a0 = As[ty * 4 + 0][kk];
            float a1 = As[ty * 4 + 1][kk];
            float a2 = As[ty * 4 + 2][kk];
            float a3 = As[ty * 4 + 3][kk];
            float4 b = *(float4*)(&Bs[kk][tx * 4]);
            acc[0][0] += a0 * b.x; acc[0][1] += a0 * b.y; acc[0][2] += a0 * b.z; acc[0][3] += a0 * b.w;
            acc[1][0] += a1 * b.x; acc[1][1] += a1 * b.y; acc[1][2] += a1 * b.z; acc[1][3] += a1 * b.w;
            acc[2][0] += a2 * b.x; acc[2][1] += a2 * b.y; acc[2][2] += a2 * b.z; acc[2][3] += a2 * b.w;
            acc[3][0] += a3 * b.x; acc[3][1] += a3 * b.y; acc[3][2] += a3 * b.z; acc[3][3] += a3 * b.w;
        }
        __syncthreads();
    }
    #pragma unroll
    for (int i = 0; i < 4; ++i) {
        int row = m0 + ty * 4 + i;
        if (row < M) {
            float4 v = make_float4(acc[i][0], acc[i][1], acc[i][2], acc[i][3]);
            *(float4*)(C + row * 256 + n0 + tx * 4) = v;
        }
    }
}

// -------- el/er: per (n,h), dot(feat[n,h,:], attn[h,:]) over D=64 (one wave) --------
__global__ __launch_bounds__(256) void eler_kernel(const float* __restrict__ feat,
                                                   const float* __restrict__ al,
                                                   const float* __restrict__ ar,
                                                   float* __restrict__ el,
                                                   float* __restrict__ er) {
    int wave = blockIdx.x * 4 + (threadIdx.x >> 6);
    int lane = threadIdx.x & 63;
    int n = wave >> 2, h = wave & 3;
    float f = feat[n * NF + h * ND + lane];
    float l = f * al[h * ND + lane];
    float r = f * ar[h * ND + lane];
    #pragma unroll
    for (int m = 32; m >= 1; m >>= 1) {
        l += __shfl_xor(l, m, 64);
        r += __shfl_xor(r, m, 64);
    }
    if (lane == 0) { el[n * NH + h] = l; er[n * NH + h] = r; }
}

// -------- per edge: ee = exp(leaky(el[src]+er[dst])); denom[dst] += ee --------
__global__ __launch_bounds__(256) void edge_kernel(const int* __restrict__ src,
                                                   const int* __restrict__ dst,
                                                   const float* __restrict__ el,
                                                   const float* __restrict__ er,
                                                   float* __restrict__ ee,
                                                   float* __restrict__ denom) {
    int e = blockIdx.x * 256 + threadIdx.x;
    if (e >= N_EDGES) return;
    int s = src[e], d = dst[e];
    float4 lv = *(const float4*)(el + s * 4);
    float4 rv = *(const float4*)(er + d * 4);
    float l[4] = {lv.x, lv.y, lv.z, lv.w};
    float r[4] = {rv.x, rv.y, rv.z, rv.w};
    float o[4];
    #pragma unroll
    for (int h = 0; h < 4; ++h) {
        float v = l[h] + r[h];
        v = v > 0.f ? v : NEG_SLOPE * v;
        float x = __expf(v);
        o[h] = x;
        atomicAdd(&denom[d * 4 + h], x);
    }
    *(float4*)(ee + e * 4) = make_float4(o[0], o[1], o[2], o[3]);
}

// -------- CSR build --------
__global__ __launch_bounds__(256) void hist_kernel(const int* __restrict__ dst, int* __restrict__ count) {
    int e = blockIdx.x * 256 + threadIdx.x;
    if (e < N_EDGES) atomicAdd(&count[dst[e]], 1);
}

__global__ __launch_bounds__(256) void scan1_kernel(const int* __restrict__ counts,
                                                    int* __restrict__ offs,
                                                    int* __restrict__ bsums) {
    __shared__ int sh[256];
    int tid = threadIdx.x;
    int i = blockIdx.x * 256 + tid;
    int v = (i < N_NODES) ? counts[i] : 0;
    sh[tid] = v;
    __syncthreads();
    #pragma unroll
    for (int ofs = 1; ofs < 256; ofs <<= 1) {
        int t = (tid >= ofs) ? sh[tid - ofs] : 0;
        __syncthreads();
        sh[tid] += t;
        __syncthreads();
    }
    if (i < N_NODES) offs[i] = sh[tid] - v;   // exclusive within block
    if (tid == 255) bsums[blockIdx.x] = sh[255];
}

__global__ __launch_bounds__(256) void scan2_kernel(const int* __restrict__ bsums,
                                                    int* __restrict__ boffs, int nb) {
    __shared__ int sh[256];
    int tid = threadIdx.x;
    int v = (tid < nb) ? bsums[tid] : 0;
    sh[tid] = v;
    __syncthreads();
    #pragma unroll
    for (int ofs = 1; ofs < 256; ofs <<= 1) {
        int t = (tid >= ofs) ? sh[tid - ofs] : 0;
        __syncthreads();
        sh[tid] += t;
        __syncthreads();
    }
    if (tid < nb) boffs[tid] = sh[tid] - v;
}

__global__ __launch_bounds__(256) void scan3_kernel(int* __restrict__ offs,
                                                    const int* __restrict__ boffs) {
    int i = blockIdx.x * 256 + threadIdx.x;
    if (i < N_NODES) offs[i] += boffs[i >> 8];
    if (i == 0) offs[N_NODES] = N_EDGES;
}

__global__ __launch_bounds__(256) void scatter_kernel(const int* __restrict__ dst,
                                                      const int* __restrict__ offs,
                                                      int* __restrict__ cursor,
                                                      int* __restrict__ csr) {
    int e = blockIdx.x * 256 + threadIdx.x;
    if (e >= N_EDGES) return;
    int d = dst[e];
    int p = atomicAdd(&cursor[d], 1);
    csr[offs[d] + p] = e;
}

// -------- aggregation: one wave per node; lane = float4 chunk of the 256 feats --------
__global__ __launch_bounds__(256) void agg_kernel(const float* __restrict__ feat,
                                                  const int* __restrict__ src,
                                                  const int* __restrict__ csr,
                                                  const int* __restrict__ offs,
                                                  const float* __restrict__ ee,
                                                  const float* __restrict__ denom,
                                                  float* __restrict__ out) {
    int n = blockIdx.x * 4 + (threadIdx.x >> 6);
    int lane = threadIdx.x & 63;
    int h = lane >> 4;
    float inv = 1.f / fmaxf(denom[n * 4 + h], 1e-9f);
    int s0 = offs[n], s1 = offs[n + 1];
    float4 acc = make_float4(0.f, 0.f, 0.f, 0.f);
    for (int i = s0; i < s1; ++i) {
        int e = csr[i];
        int s = src[e];
        float4 f = *(const float4*)(feat + s * NF + lane * 4);
        float w = ee[e * 4 + h] * inv;
        acc.x += f.x * w; acc.y += f.y * w; acc.z += f.z * w; acc.w += f.w * w;
    }
    float4 o = make_float4(elu_f(acc.x), elu_f(acc.y), elu_f(acc.z), elu_f(acc.w));
    *(float4*)(out + n * NF + lane * 4) = o;
}

// -------- final: aggregate layer2 + elu + write heads + cluster softmax --------
__global__ __launch_bounds__(256) void agg_final_kernel(const float* __restrict__ feat,
                                                        const int* __restrict__ src,
                                                        const int* __restrict__ csr,
                                                        const int* __restrict__ offs,
                                                        const float* __restrict__ ee,
                                                        const float* __restrict__ denom,
                                                        const float* __restrict__ Wc,
                                                        const float* __restrict__ bc,
                                                        float* __restrict__ out) {
    int n = blockIdx.x * 4 + (threadIdx.x >> 6);
    int lane = threadIdx.x & 63;
    int h = lane >> 4;
    int g = lane & 15;
    float inv = 1.f / fmaxf(denom[n * 4 + h], 1e-9f);
    int s0 = offs[n], s1 = offs[n + 1];
    float4 acc = make_float4(0.f, 0.f, 0.f, 0.f);
    for (int i = s0; i < s1; ++i) {
        int e = csr[i];
        int s = src[e];
        float4 f = *(const float4*)(feat + s * NF + lane * 4);
        float w = ee[e * 4 + h] * inv;
        acc.x += f.x * w; acc.y += f.y * w; acc.z += f.z * w; acc.w += f.w * w;
    }
    float v0 = elu_f(acc.x), v1 = elu_f(acc.y), v2 = elu_f(acc.z), v3 = elu_f(acc.w);
    // heads: out[h, n, 0:64]
    size_t base = (size_t)h * N_NODES * (ND + NC) + (size_t)n * (ND + NC);
    *(float4*)(out + base + g * 4) = make_float4(v0, v1, v2, v3);
    // cluster logits: dot over d (64) of heads[n,h,:] with Wc[:,c]; 16-lane butterfly
    float logit[NC];
    #pragma unroll
    for (int c = 0; c < NC; ++c) {
        int d0 = g * 4;
        float p = v0 * Wc[(d0 + 0) * NC + c] + v1 * Wc[(d0 + 1) * NC + c] +
                  v2 * Wc[(d0 + 2) * NC + c] + v3 * Wc[(d0 + 3) * NC + c];
        p += __shfl_xor(p, 1, 64);
        p += __shfl_xor(p, 2, 64);
        p += __shfl_xor(p, 4, 64);
        p += __shfl_xor(p, 8, 64);
        logit[c] = p + bc[c];
    }
    float m = logit[0];
    #pragma unroll
    for (int c = 1; c < NC; ++c) m = fmaxf(m, logit[c]);
    float ssum = 0.f;
    #pragma unroll
    for (int c = 0; c < NC; ++c) ssum += __expf(logit[c] - m);
    out[base + ND + g] = __expf(logit[g] - m) / ssum;
}

extern "C" void kernel_launch(void* const* d_in, const int* in_sizes, int n_in,
                              void* d_out, int out_size, void* d_ws, size_t ws_size,
                              hipStream_t stream) {
    const float* x   = (const float*)d_in[0];
    const int* src   = (const int*)d_in[1];
    const int* dst   = (const int*)d_in[2];
    const float* W0  = (const float*)d_in[3];
    const float* al0 = (const float*)d_in[4];
    const float* ar0 = (const float*)d_in[5];
    const float* W1  = (const float*)d_in[6];
    const float* al1 = (const float*)d_in[7];
    const float* ar1 = (const float*)d_in[8];
    const float* Wc  = (const float*)d_in[9];
    const float* bc  = (const float*)d_in[10];
    float* out = (float*)d_out;

    char* ws = (char*)d_ws;
    size_t off = 0;
    auto alloc = [&](size_t bytes) { void* p = ws + off; off = (off + bytes + 255) & ~(size_t)255; return p; };
    float* feat   = (float*)alloc((size_t)N_NODES * NF * 4);   // 51.2 MB
    float* hbuf   = (float*)alloc((size_t)N_NODES * NF * 4);   // 51.2 MB
    float* el     = (float*)alloc((size_t)N_NODES * NH * 4);
    float* er     = (float*)alloc((size_t)N_NODES * NH * 4);
    float* ee     = (float*)alloc((size_t)N_EDGES * NH * 4);   // 12.8 MB
    float* denom  = (float*)alloc((size_t)N_NODES * NH * 4);
    int* counts   = (int*)alloc((size_t)N_NODES * 4);
    int* offs     = (int*)alloc((size_t)(N_NODES + 1) * 4);
    int* cursor   = (int*)alloc((size_t)N_NODES * 4);
    int* csr      = (int*)alloc((size_t)N_EDGES * 4);
    int* bsums    = (int*)alloc(256 * 4);
    int* boffs    = (int*)alloc(256 * 4);

    const int EB = (N_EDGES + 255) / 256;          // 3125
    const int NB = (N_NODES + 255) / 256;          // 196
    const int GEMM_MB = (N_NODES + 63) / 64;       // 782

    // ---- CSR build (graph is static per call) ----
    hipMemsetAsync(counts, 0, (size_t)N_NODES * 4, stream);
    hist_kernel<<<EB, 256, 0, stream>>>(dst, counts);
    scan1_kernel<<<NB, 256, 0, stream>>>(counts, offs, bsums);
    scan2_kernel<<<1, 256, 0, stream>>>(bsums, boffs, NB);
    scan3_kernel<<<NB, 256, 0, stream>>>(offs, boffs);
    hipMemsetAsync(cursor, 0, (size_t)N_NODES * 4, stream);
    scatter_kernel<<<EB, 256, 0, stream>>>(dst, offs, cursor, csr);

    // ---- Layer 0 ----
    gemm256<<<dim3(GEMM_MB, 4), 256, 0, stream>>>(x, W0, feat, N_NODES);
    eler_kernel<<<N_NODES, 256, 0, stream>>>(feat, al0, ar0, el, er);
    hipMemsetAsync(denom, 0, (size_t)N_NODES * NH * 4, stream);
    edge_kernel<<<EB, 256, 0, stream>>>(src, dst, el, er, ee, denom);
    agg_kernel<<<N_NODES / 4, 256, 0, stream>>>(feat, src, csr, offs, ee, denom, hbuf);

    // ---- Layer 1 ----
    gemm256<<<dim3(GEMM_MB, 4), 256, 0, stream>>>(hbuf, W1, feat, N_NODES);
    eler_kernel<<<N_NODES, 256, 0, stream>>>(feat, al1, ar1, el, er);
    hipMemsetAsync(denom, 0, (size_t)N_NODES * NH * 4, stream);
    edge_kernel<<<EB, 256, 0, stream>>>(src, dst, el, er, ee, denom);
    agg_final_kernel<<<N_NODES / 4, 256, 0, stream>>>(feat, src, csr, offs, ee, denom, Wc, bc, out);
}

// Round 2
// 493.252 us; speedup vs baseline: 2.0385x; 2.0385x over previous
//
#include <hip/hip_runtime.h>
#include <hip/hip_bf16.h>
#include <math.h>

#define N_NODES 50000
#define N_EDGES 800000
#define NH 4
#define ND 64
#define NF 256   // NH*ND = feature width everywhere (IN=256 too)
#define NC 16
#define NEG_SLOPE 0.2f

typedef __attribute__((ext_vector_type(8))) short bf16x8;
typedef __attribute__((ext_vector_type(4))) float f32x4;

__device__ __forceinline__ float elu_f(float x) {
    return x > 0.f ? x : (__expf(x) - 1.f);
}

__device__ __forceinline__ ushort bf16_rne(float f) {
    union { float f; unsigned u; } v; v.f = f;
    unsigned u = v.u;
    u += 0x7fffu + ((u >> 16) & 1u);   // round-to-nearest-even
    return (ushort)(u >> 16);
}

// ---------------- cast x (f32) -> bf16 ----------------
__global__ __launch_bounds__(256) void cast_bf16_kernel(const float* __restrict__ in,
                                                        ushort* __restrict__ out, int n8) {
    int i = blockIdx.x * 256 + threadIdx.x;
    if (i >= n8) return;
    float4 a = *(const float4*)(in + i * 8);
    float4 b = *(const float4*)(in + i * 8 + 4);
    ushort o[8] = {bf16_rne(a.x), bf16_rne(a.y), bf16_rne(a.z), bf16_rne(a.w),
                   bf16_rne(b.x), bf16_rne(b.y), bf16_rne(b.z), bf16_rne(b.w)};
    *(bf16x8*)(out + i * 8) = *(bf16x8*)o;
}

// ---- transpose+cast W[k][n] f32 -> Wt[n][k] bf16, two weights in one launch ----
__global__ __launch_bounds__(256) void castWt_kernel(const float* __restrict__ W0,
                                                     const float* __restrict__ W1,
                                                     ushort* __restrict__ Wt0,
                                                     ushort* __restrict__ Wt1) {
    const float* W = (blockIdx.x < 256) ? W0 : W1;
    ushort* Wt = (blockIdx.x < 256) ? Wt0 : Wt1;
    int n = blockIdx.x & 255;
    int k = threadIdx.x;
    Wt[n * 256 + k] = bf16_rne(W[k * 256 + n]);
}

// ---------------- GEMM: C[M,256] f32 = A[M,256]bf16 @ B, Bt[n][k] bf16 ----------------
// 128x128 tile, BK=64, 256 threads (4 waves 2x2), 16x16x32 MFMA, XOR-swizzled LDS.
__global__ __launch_bounds__(256) void gemm_bf16(const ushort* __restrict__ A,
                                                 const ushort* __restrict__ Bt,
                                                 float* __restrict__ C, int M) {
    __shared__ __align__(16) ushort As[128 * 64];   // [row][k], 16B blocks XOR-swizzled
    __shared__ __align__(16) ushort Bs[128 * 64];   // [col][k], same
    const int t = threadIdx.x;
    const int l = t & 63;
    const int w = t >> 6;
    const int wm = (w >> 1) * 64, wn = (w & 1) * 64;
    const int m0 = blockIdx.x * 128, n0 = blockIdx.y * 128;
    const int lr = l & 15, lk = l >> 4;

    f32x4 acc[4][4] = {};
    const int sr = t >> 3;            // staging row-in-issue 0..31
    const int sc = t & 7;             // global 16B-block col
    const int scw = sc ^ (sr & 7);    // swizzled LDS block

    for (int k0 = 0; k0 < 256; k0 += 64) {
        #pragma unroll
        for (int q = 0; q < 4; ++q) {
            int row = q * 32 + sr;
            int ga = min(m0 + row, M - 1);
            bf16x8 va = *(const bf16x8*)(A + (size_t)ga * 256 + k0 + sc * 8);
            *(bf16x8*)(&As[row * 64 + scw * 8]) = va;
            bf16x8 vb = *(const bf16x8*)(Bt + (size_t)(n0 + row) * 256 + k0 + sc * 8);
            *(bf16x8*)(&Bs[row * 64 + scw * 8]) = vb;
        }
        __syncthreads();
        #pragma unroll
        for (int kk = 0; kk < 2; ++kk) {
            bf16x8 af[4], bfr[4];
            #pragma unroll
            for (int mi = 0; mi < 4; ++mi) {
                int row = wm + mi * 16 + lr;
                int kb = kk * 4 + lk;
                af[mi] = *(const bf16x8*)(&As[row * 64 + (kb ^ (row & 7)) * 8]);
            }
            #pragma unroll
            for (int ni = 0; ni < 4; ++ni) {
                int col = wn + ni * 16 + lr;
                int kb = kk * 4 + lk;
                bfr[ni] = *(const bf16x8*)(&Bs[col * 64 + (kb ^ (col & 7)) * 8]);
            }
            #pragma unroll
            for (int mi = 0; mi < 4; ++mi)
                #pragma unroll
                for (int ni = 0; ni < 4; ++ni)
                    acc[mi][ni] = __builtin_amdgcn_mfma_f32_16x16x32_bf16(af[mi], bfr[ni], acc[mi][ni], 0, 0, 0);
        }
        __syncthreads();
    }
    // C/D layout: col = lane&15, row = (lane>>4)*4 + reg  [m89-verified]
    #pragma unroll
    for (int mi = 0; mi < 4; ++mi) {
        #pragma unroll
        for (int j = 0; j < 4; ++j) {
            int row = m0 + wm + mi * 16 + lk * 4 + j;
            if (row < M) {
                #pragma unroll
                for (int ni = 0; ni < 4; ++ni)
                    C[(size_t)row * 256 + n0 + wn + ni * 16 + lr] = acc[mi][ni][j];
            }
        }
    }
}

// -------- el/er: per (n,h), dot(feat[n,h,:], attn[h,:]) over D=64 (one wave) --------
__global__ __launch_bounds__(256) void eler_kernel(const float* __restrict__ feat,
                                                   const float* __restrict__ al,
                                                   const float* __restrict__ ar,
                                                   float* __restrict__ el,
                                                   float* __restrict__ er) {
    int wave = blockIdx.x * 4 + (threadIdx.x >> 6);
    int lane = threadIdx.x & 63;
    int n = wave >> 2, h = wave & 3;
    float f = feat[n * NF + h * ND + lane];
    float l = f * al[h * ND + lane];
    float r = f * ar[h * ND + lane];
    #pragma unroll
    for (int m = 32; m >= 1; m >>= 1) {
        l += __shfl_xor(l, m, 64);
        r += __shfl_xor(r, m, 64);
    }
    if (lane == 0) { el[n * NH + h] = l; er[n * NH + h] = r; }
}

// -------- CSR build --------
__global__ __launch_bounds__(256) void hist_kernel(const int* __restrict__ dst, int* __restrict__ count) {
    int e = blockIdx.x * 256 + threadIdx.x;
    if (e < N_EDGES) atomicAdd(&count[dst[e]], 1);
}

__global__ __launch_bounds__(256) void scan1_kernel(const int* __restrict__ counts,
                                                    int* __restrict__ offs,
                                                    int* __restrict__ bsums) {
    __shared__ int sh[256];
    int tid = threadIdx.x;
    int i = blockIdx.x * 256 + tid;
    int v = (i < N_NODES) ? counts[i] : 0;
    sh[tid] = v;
    __syncthreads();
    #pragma unroll
    for (int ofs = 1; ofs < 256; ofs <<= 1) {
        int t = (tid >= ofs) ? sh[tid - ofs] : 0;
        __syncthreads();
        sh[tid] += t;
        __syncthreads();
    }
    if (i < N_NODES) offs[i] = sh[tid] - v;
    if (tid == 255) bsums[blockIdx.x] = sh[255];
}

__global__ __launch_bounds__(256) void scan2_kernel(const int* __restrict__ bsums,
                                                    int* __restrict__ boffs, int nb) {
    __shared__ int sh[256];
    int tid = threadIdx.x;
    int v = (tid < nb) ? bsums[tid] : 0;
    sh[tid] = v;
    __syncthreads();
    #pragma unroll
    for (int ofs = 1; ofs < 256; ofs <<= 1) {
        int t = (tid >= ofs) ? sh[tid - ofs] : 0;
        __syncthreads();
        sh[tid] += t;
        __syncthreads();
    }
    if (tid < nb) boffs[tid] = sh[tid] - v;
}

__global__ __launch_bounds__(256) void scan3_kernel(int* __restrict__ offs,
                                                    const int* __restrict__ boffs) {
    int i = blockIdx.x * 256 + threadIdx.x;
    if (i < N_NODES) offs[i] += boffs[i >> 8];
    if (i == 0) offs[N_NODES] = N_EDGES;
}

__global__ __launch_bounds__(256) void scatter_kernel(const int* __restrict__ dst,
                                                      const int* __restrict__ offs,
                                                      int* __restrict__ cursor,
                                                      int* __restrict__ csr) {
    int e = blockIdx.x * 256 + threadIdx.x;
    if (e >= N_EDGES) return;
    int d = dst[e];
    int p = atomicAdd(&cursor[d], 1);
    csr[offs[d] + p] = e;
}

// -------- fused aggregation: attention weights computed inline, denom in-register --------
// one wave per node; lane = float4 chunk; 4-edge batched for MLP.
// Layer-0 variant: writes bf16 output (consumed only by GEMM-1).
#define AGG_EDGE(S, EL)                                                    \
    {                                                                      \
        float v = (EL) + er_n;                                             \
        v = v > 0.f ? v : NEG_SLOPE * v;                                   \
        float wgt = __expf(v);                                             \
        dsum += wgt;                                                       \
        float4 f = *(const float4*)(feat + (size_t)(S) * NF + lane * 4);   \
        acc.x += wgt * f.x; acc.y += wgt * f.y;                            \
        acc.z += wgt * f.z; acc.w += wgt * f.w;                            \
    }

__global__ __launch_bounds__(256) void agg_l0_kernel(const float* __restrict__ feat,
                                                     const int* __restrict__ src,
                                                     const int* __restrict__ csr,
                                                     const int* __restrict__ offs,
                                                     const float* __restrict__ el,
                                                     const float* __restrict__ er,
                                                     ushort* __restrict__ out_bf) {
    int n = blockIdx.x * 4 + (threadIdx.x >> 6);
    int lane = threadIdx.x & 63;
    int h = lane >> 4;
    float er_n = er[n * 4 + h];
    int s0 = offs[n], s1 = offs[n + 1];
    float4 acc = make_float4(0.f, 0.f, 0.f, 0.f);
    float dsum = 0.f;
    int i = s0;
    for (; i + 4 <= s1; i += 4) {
        int e0 = csr[i], e1 = csr[i + 1], e2 = csr[i + 2], e3 = csr[i + 3];
        int sA = src[e0], sB = src[e1], sC = src[e2], sD = src[e3];
        float lA = el[sA * 4 + h], lB = el[sB * 4 + h], lC = el[sC * 4 + h], lD = el[sD * 4 + h];
        AGG_EDGE(sA, lA); AGG_EDGE(sB, lB); AGG_EDGE(sC, lC); AGG_EDGE(sD, lD);
    }
    for (; i < s1; ++i) {
        int e = csr[i];
        int s = src[e];
        float lv = el[s * 4 + h];
        AGG_EDGE(s, lv);
    }
    float inv = 1.f / fmaxf(dsum, 1e-9f);
    ushort o[4] = {bf16_rne(elu_f(acc.x * inv)), bf16_rne(elu_f(acc.y * inv)),
                   bf16_rne(elu_f(acc.z * inv)), bf16_rne(elu_f(acc.w * inv))};
    *(ushort4*)(out_bf + (size_t)n * NF + lane * 4) = *(ushort4*)o;
}

// -------- final: fused aggregation + elu + heads write + cluster softmax --------
__global__ __launch_bounds__(256) void agg_final_kernel(const float* __restrict__ feat,
                                                        const int* __restrict__ src,
                                                        const int* __restrict__ csr,
                                                        const int* __restrict__ offs,
                                                        const float* __restrict__ el,
                                                        const float* __restrict__ er,
                                                        const float* __restrict__ Wc,
                                                        const float* __restrict__ bc,
                                                        float* __restrict__ out) {
    int n = blockIdx.x * 4 + (threadIdx.x >> 6);
    int lane = threadIdx.x & 63;
    int h = lane >> 4;
    int g = lane & 15;
    float er_n = er[n * 4 + h];
    int s0 = offs[n], s1 = offs[n + 1];
    float4 acc = make_float4(0.f, 0.f, 0.f, 0.f);
    float dsum = 0.f;
    int i = s0;
    for (; i + 4 <= s1; i += 4) {
        int e0 = csr[i], e1 = csr[i + 1], e2 = csr[i + 2], e3 = csr[i + 3];
        int sA = src[e0], sB = src[e1], sC = src[e2], sD = src[e3];
        float lA = el[sA * 4 + h], lB = el[sB * 4 + h], lC = el[sC * 4 + h], lD = el[sD * 4 + h];
        AGG_EDGE(sA, lA); AGG_EDGE(sB, lB); AGG_EDGE(sC, lC); AGG_EDGE(sD, lD);
    }
    for (; i < s1; ++i) {
        int e = csr[i];
        int s = src[e];
        float lv = el[s * 4 + h];
        AGG_EDGE(s, lv);
    }
    float inv = 1.f / fmaxf(dsum, 1e-9f);
    float v0 = elu_f(acc.x * inv), v1 = elu_f(acc.y * inv);
    float v2 = elu_f(acc.z * inv), v3 = elu_f(acc.w * inv);
    size_t base = (size_t)h * N_NODES * (ND + NC) + (size_t)n * (ND + NC);
    *(float4*)(out + base + g * 4) = make_float4(v0, v1, v2, v3);
    float logit[NC];
    #pragma unroll
    for (int c = 0; c < NC; ++c) {
        int d0 = g * 4;
        float p = v0 * Wc[(d0 + 0) * NC + c] + v1 * Wc[(d0 + 1) * NC + c] +
                  v2 * Wc[(d0 + 2) * NC + c] + v3 * Wc[(d0 + 3) * NC + c];
        p += __shfl_xor(p, 1, 64);
        p += __shfl_xor(p, 2, 64);
        p += __shfl_xor(p, 4, 64);
        p += __shfl_xor(p, 8, 64);
        logit[c] = p + bc[c];
    }
    float m = logit[0];
    #pragma unroll
    for (int c = 1; c < NC; ++c) m = fmaxf(m, logit[c]);
    float ssum = 0.f;
    #pragma unroll
    for (int c = 0; c < NC; ++c) ssum += __expf(logit[c] - m);
    out[base + ND + g] = __expf(logit[g] - m) / ssum;
}

extern "C" void kernel_launch(void* const* d_in, const int* in_sizes, int n_in,
                              void* d_out, int out_size, void* d_ws, size_t ws_size,
                              hipStream_t stream) {
    const float* x   = (const float*)d_in[0];
    const int* src   = (const int*)d_in[1];
    const int* dst   = (const int*)d_in[2];
    const float* W0  = (const float*)d_in[3];
    const float* al0 = (const float*)d_in[4];
    const float* ar0 = (const float*)d_in[5];
    const float* W1  = (const float*)d_in[6];
    const float* al1 = (const float*)d_in[7];
    const float* ar1 = (const float*)d_in[8];
    const float* Wc  = (const float*)d_in[9];
    const float* bc  = (const float*)d_in[10];
    float* out = (float*)d_out;

    char* ws = (char*)d_ws;
    size_t off = 0;
    auto alloc = [&](size_t bytes) { void* p = ws + off; off = (off + bytes + 255) & ~(size_t)255; return p; };
    float*  feat  = (float*)alloc((size_t)N_NODES * NF * 4);    // 51.2 MB (f32 GEMM out)
    ushort* xbf   = (ushort*)alloc((size_t)N_NODES * NF * 2);   // 25.6 MB
    ushort* hbuf  = (ushort*)alloc((size_t)N_NODES * NF * 2);   // 25.6 MB (layer0 out, bf16)
    ushort* Wt0   = (ushort*)alloc((size_t)256 * 256 * 2);
    ushort* Wt1   = (ushort*)alloc((size_t)256 * 256 * 2);
    float*  el    = (float*)alloc((size_t)N_NODES * NH * 4);
    float*  er    = (float*)alloc((size_t)N_NODES * NH * 4);
    int* counts   = (int*)alloc((size_t)N_NODES * 4);
    int* offs     = (int*)alloc((size_t)(N_NODES + 1) * 4);
    int* cursor   = (int*)alloc((size_t)N_NODES * 4);
    int* csr      = (int*)alloc((size_t)N_EDGES * 4);
    int* bsums    = (int*)alloc(256 * 4);
    int* boffs    = (int*)alloc(256 * 4);

    const int EB = (N_EDGES + 255) / 256;          // 3125
    const int NB = (N_NODES + 255) / 256;          // 196
    const int GEMM_MB = (N_NODES + 127) / 128;     // 391
    const int C8 = (N_NODES * NF / 8 + 255) / 256; // cast blocks

    // ---- CSR build ----
    hipMemsetAsync(counts, 0, (size_t)N_NODES * 4, stream);
    hist_kernel<<<EB, 256, 0, stream>>>(dst, counts);
    scan1_kernel<<<NB, 256, 0, stream>>>(counts, offs, bsums);
    scan2_kernel<<<1, 256, 0, stream>>>(bsums, boffs, NB);
    scan3_kernel<<<NB, 256, 0, stream>>>(offs, boffs);
    hipMemsetAsync(cursor, 0, (size_t)N_NODES * 4, stream);
    scatter_kernel<<<EB, 256, 0, stream>>>(dst, offs, cursor, csr);

    // ---- weight + input casts ----
    castWt_kernel<<<512, 256, 0, stream>>>(W0, W1, Wt0, Wt1);
    cast_bf16_kernel<<<C8, 256, 0, stream>>>(x, xbf, N_NODES * NF / 8);

    // ---- Layer 0 ----
    gemm_bf16<<<dim3(GEMM_MB, 2), 256, 0, stream>>>(xbf, Wt0, feat, N_NODES);
    eler_kernel<<<N_NODES, 256, 0, stream>>>(feat, al0, ar0, el, er);
    agg_l0_kernel<<<N_NODES / 4, 256, 0, stream>>>(feat, src, csr, offs, el, er, hbuf);

    // ---- Layer 1 ----
    gemm_bf16<<<dim3(GEMM_MB, 2), 256, 0, stream>>>(hbuf, Wt1, feat, N_NODES);
    eler_kernel<<<N_NODES, 256, 0, stream>>>(feat, al1, ar1, el, er);
    agg_final_kernel<<<N_NODES / 4, 256, 0, stream>>>(feat, src, csr, offs, el, er, Wc, bc, out);
}

// Round 3
// 421.906 us; speedup vs baseline: 2.3832x; 1.1691x over previous
//
#include <hip/hip_runtime.h>
#include <hip/hip_bf16.h>
#include <math.h>

#define N_NODES 50000
#define N_EDGES 800000
#define NH 4
#define ND 64
#define NF 256   // NH*ND = feature width everywhere (IN=256 too)
#define NC 16
#define NEG_SLOPE 0.2f

typedef __attribute__((ext_vector_type(8))) short bf16x8;
typedef __attribute__((ext_vector_type(4))) float f32x4;

__device__ __forceinline__ float elu_f(float x) {
    return x > 0.f ? x : (__expf(x) - 1.f);
}

__device__ __forceinline__ ushort bf16_rne(float f) {
    union { float f; unsigned u; } v; v.f = f;
    unsigned u = v.u;
    u += 0x7fffu + ((u >> 16) & 1u);   // round-to-nearest-even
    return (ushort)(u >> 16);
}

__device__ __forceinline__ float bf2f(ushort u) {
    return __uint_as_float(((unsigned)u) << 16);
}

// ---------------- cast x (f32) -> bf16 ----------------
__global__ __launch_bounds__(256) void cast_bf16_kernel(const float* __restrict__ in,
                                                        ushort* __restrict__ out, int n8) {
    int i = blockIdx.x * 256 + threadIdx.x;
    if (i >= n8) return;
    float4 a = *(const float4*)(in + i * 8);
    float4 b = *(const float4*)(in + i * 8 + 4);
    ushort o[8] = {bf16_rne(a.x), bf16_rne(a.y), bf16_rne(a.z), bf16_rne(a.w),
                   bf16_rne(b.x), bf16_rne(b.y), bf16_rne(b.z), bf16_rne(b.w)};
    *(bf16x8*)(out + i * 8) = *(bf16x8*)o;
}

// ---- transpose+cast W[k][n] f32 -> Wt[n][k] bf16, two weights in one launch ----
__global__ __launch_bounds__(256) void castWt_kernel(const float* __restrict__ W0,
                                                     const float* __restrict__ W1,
                                                     ushort* __restrict__ Wt0,
                                                     ushort* __restrict__ Wt1) {
    const float* W = (blockIdx.x < 256) ? W0 : W1;
    ushort* Wt = (blockIdx.x < 256) ? Wt0 : Wt1;
    int n = blockIdx.x & 255;
    int k = threadIdx.x;
    Wt[n * 256 + k] = bf16_rne(W[k * 256 + n]);
}

// ---------------- GEMM: C[M,256] = A[M,256]bf16 @ Bt[n][k]bf16 ----------------
// 128x128 tile, BK=64, 256 threads (4 waves 2x2), 16x16x32 MFMA, XOR-swizzled LDS.
// Dual epilogue: f32 C (for el/er precision) + bf16 Cbf (for the edge gather).
__global__ __launch_bounds__(256) void gemm_bf16(const ushort* __restrict__ A,
                                                 const ushort* __restrict__ Bt,
                                                 float* __restrict__ C,
                                                 ushort* __restrict__ Cbf, int M) {
    __shared__ __align__(16) ushort As[128 * 64];   // [row][k], 16B blocks XOR-swizzled
    __shared__ __align__(16) ushort Bs[128 * 64];   // [col][k], same
    const int t = threadIdx.x;
    const int l = t & 63;
    const int w = t >> 6;
    const int wm = (w >> 1) * 64, wn = (w & 1) * 64;
    const int m0 = blockIdx.x * 128, n0 = blockIdx.y * 128;
    const int lr = l & 15, lk = l >> 4;

    f32x4 acc[4][4] = {};
    const int sr = t >> 3;            // staging row-in-issue 0..31
    const int sc = t & 7;             // global 16B-block col
    const int scw = sc ^ (sr & 7);    // swizzled LDS block

    for (int k0 = 0; k0 < 256; k0 += 64) {
        #pragma unroll
        for (int q = 0; q < 4; ++q) {
            int row = q * 32 + sr;
            int ga = min(m0 + row, M - 1);
            bf16x8 va = *(const bf16x8*)(A + (size_t)ga * 256 + k0 + sc * 8);
            *(bf16x8*)(&As[row * 64 + scw * 8]) = va;
            bf16x8 vb = *(const bf16x8*)(Bt + (size_t)(n0 + row) * 256 + k0 + sc * 8);
            *(bf16x8*)(&Bs[row * 64 + scw * 8]) = vb;
        }
        __syncthreads();
        #pragma unroll
        for (int kk = 0; kk < 2; ++kk) {
            bf16x8 af[4], bfr[4];
            #pragma unroll
            for (int mi = 0; mi < 4; ++mi) {
                int row = wm + mi * 16 + lr;
                int kb = kk * 4 + lk;
                af[mi] = *(const bf16x8*)(&As[row * 64 + (kb ^ (row & 7)) * 8]);
            }
            #pragma unroll
            for (int ni = 0; ni < 4; ++ni) {
                int col = wn + ni * 16 + lr;
                int kb = kk * 4 + lk;
                bfr[ni] = *(const bf16x8*)(&Bs[col * 64 + (kb ^ (col & 7)) * 8]);
            }
            #pragma unroll
            for (int mi = 0; mi < 4; ++mi)
                #pragma unroll
                for (int ni = 0; ni < 4; ++ni)
                    acc[mi][ni] = __builtin_amdgcn_mfma_f32_16x16x32_bf16(af[mi], bfr[ni], acc[mi][ni], 0, 0, 0);
        }
        __syncthreads();
    }
    // C/D layout: col = lane&15, row = (lane>>4)*4 + reg  [m89-verified]
    #pragma unroll
    for (int mi = 0; mi < 4; ++mi) {
        #pragma unroll
        for (int j = 0; j < 4; ++j) {
            int row = m0 + wm + mi * 16 + lk * 4 + j;
            if (row < M) {
                #pragma unroll
                for (int ni = 0; ni < 4; ++ni) {
                    int col = n0 + wn + ni * 16 + lr;
                    float v = acc[mi][ni][j];
                    C[(size_t)row * 256 + col] = v;
                    Cbf[(size_t)row * 256 + col] = bf16_rne(v);
                }
            }
        }
    }
}

// -------- el/er: per (n,h), dot(feat[n,h,:], attn[h,:]) over D=64 (one wave) --------
__global__ __launch_bounds__(256) void eler_kernel(const float* __restrict__ feat,
                                                   const float* __restrict__ al,
                                                   const float* __restrict__ ar,
                                                   float* __restrict__ el,
                                                   float* __restrict__ er) {
    int wave = blockIdx.x * 4 + (threadIdx.x >> 6);
    int lane = threadIdx.x & 63;
    int n = wave >> 2, h = wave & 3;
    float f = feat[n * NF + h * ND + lane];
    float l = f * al[h * ND + lane];
    float r = f * ar[h * ND + lane];
    #pragma unroll
    for (int m = 32; m >= 1; m >>= 1) {
        l += __shfl_xor(l, m, 64);
        r += __shfl_xor(r, m, 64);
    }
    if (lane == 0) { el[n * NH + h] = l; er[n * NH + h] = r; }
}

// -------- CSR build --------
__global__ __launch_bounds__(256) void hist_kernel(const int* __restrict__ dst, int* __restrict__ count) {
    int e = blockIdx.x * 256 + threadIdx.x;
    if (e < N_EDGES) atomicAdd(&count[dst[e]], 1);
}

__global__ __launch_bounds__(256) void scan1_kernel(const int* __restrict__ counts,
                                                    int* __restrict__ offs,
                                                    int* __restrict__ bsums) {
    __shared__ int sh[256];
    int tid = threadIdx.x;
    int i = blockIdx.x * 256 + tid;
    int v = (i < N_NODES) ? counts[i] : 0;
    sh[tid] = v;
    __syncthreads();
    #pragma unroll
    for (int ofs = 1; ofs < 256; ofs <<= 1) {
        int t = (tid >= ofs) ? sh[tid - ofs] : 0;
        __syncthreads();
        sh[tid] += t;
        __syncthreads();
    }
    if (i < N_NODES) offs[i] = sh[tid] - v;
    if (tid == 255) bsums[blockIdx.x] = sh[255];
}

__global__ __launch_bounds__(256) void scan2_kernel(const int* __restrict__ bsums,
                                                    int* __restrict__ boffs, int nb) {
    __shared__ int sh[256];
    int tid = threadIdx.x;
    int v = (tid < nb) ? bsums[tid] : 0;
    sh[tid] = v;
    __syncthreads();
    #pragma unroll
    for (int ofs = 1; ofs < 256; ofs <<= 1) {
        int t = (tid >= ofs) ? sh[tid - ofs] : 0;
        __syncthreads();
        sh[tid] += t;
        __syncthreads();
    }
    if (tid < nb) boffs[tid] = sh[tid] - v;
}

// scan3: finalize offs AND init cursor (absolute write positions)
__global__ __launch_bounds__(256) void scan3_kernel(int* __restrict__ offs,
                                                    const int* __restrict__ boffs,
                                                    int* __restrict__ cursor) {
    int i = blockIdx.x * 256 + threadIdx.x;
    if (i < N_NODES) {
        int v = offs[i] + boffs[i >> 8];
        offs[i] = v;
        cursor[i] = v;
    }
    if (i == 0) offs[N_NODES] = N_EDGES;
}

// scatter: store src node id directly (no edge-id indirection downstream)
__global__ __launch_bounds__(256) void scatter_kernel(const int* __restrict__ src,
                                                      const int* __restrict__ dst,
                                                      int* __restrict__ cursor,
                                                      int* __restrict__ csrc) {
    int e = blockIdx.x * 256 + threadIdx.x;
    if (e >= N_EDGES) return;
    int p = atomicAdd(&cursor[dst[e]], 1);
    csrc[p] = src[e];
}

// -------- fused aggregation over bf16 feature rows, 8-edge predicated batches --------
// one wave per node; lane = 4-bf16 chunk (8B) of the 256 features.
#define AGG_BATCH8(BODY_TAIL)                                                   \
    for (int i = s0; i < s1; i += 8) {                                          \
        int sid[8]; float lv[8]; ushort4 fr[8];                                 \
        _Pragma("unroll")                                                       \
        for (int u = 0; u < 8; ++u) {                                           \
            int idx = (i + u < s1) ? i + u : s1 - 1;                            \
            sid[u] = csrc[idx];                                                 \
        }                                                                       \
        _Pragma("unroll")                                                       \
        for (int u = 0; u < 8; ++u) {                                           \
            lv[u] = el[sid[u] * 4 + h];                                         \
            fr[u] = *(const ushort4*)(featbf + (size_t)sid[u] * NF + lane * 4); \
        }                                                                       \
        _Pragma("unroll")                                                       \
        for (int u = 0; u < 8; ++u) {                                           \
            float v = lv[u] + er_n;                                             \
            v = v > 0.f ? v : NEG_SLOPE * v;                                    \
            float wgt = (i + u < s1) ? __expf(v) : 0.f;                         \
            dsum += wgt;                                                        \
            acc.x += wgt * bf2f(fr[u].x);                                       \
            acc.y += wgt * bf2f(fr[u].y);                                       \
            acc.z += wgt * bf2f(fr[u].z);                                       \
            acc.w += wgt * bf2f(fr[u].w);                                       \
        }                                                                       \
    }

__global__ __launch_bounds__(256) void agg_l0_kernel(const ushort* __restrict__ featbf,
                                                     const int* __restrict__ csrc,
                                                     const int* __restrict__ offs,
                                                     const float* __restrict__ el,
                                                     const float* __restrict__ er,
                                                     ushort* __restrict__ out_bf) {
    int n = blockIdx.x * 4 + (threadIdx.x >> 6);
    int lane = threadIdx.x & 63;
    int h = lane >> 4;
    float er_n = er[n * 4 + h];
    int s0 = offs[n], s1 = offs[n + 1];
    float4 acc = make_float4(0.f, 0.f, 0.f, 0.f);
    float dsum = 0.f;
    AGG_BATCH8()
    float inv = 1.f / fmaxf(dsum, 1e-9f);
    ushort o[4] = {bf16_rne(elu_f(acc.x * inv)), bf16_rne(elu_f(acc.y * inv)),
                   bf16_rne(elu_f(acc.z * inv)), bf16_rne(elu_f(acc.w * inv))};
    *(ushort4*)(out_bf + (size_t)n * NF + lane * 4) = *(ushort4*)o;
}

// -------- final: fused aggregation + elu + heads write + cluster softmax --------
__global__ __launch_bounds__(256) void agg_final_kernel(const ushort* __restrict__ featbf,
                                                        const int* __restrict__ csrc,
                                                        const int* __restrict__ offs,
                                                        const float* __restrict__ el,
                                                        const float* __restrict__ er,
                                                        const float* __restrict__ Wc,
                                                        const float* __restrict__ bc,
                                                        float* __restrict__ out) {
    int n = blockIdx.x * 4 + (threadIdx.x >> 6);
    int lane = threadIdx.x & 63;
    int h = lane >> 4;
    int g = lane & 15;
    float er_n = er[n * 4 + h];
    int s0 = offs[n], s1 = offs[n + 1];
    float4 acc = make_float4(0.f, 0.f, 0.f, 0.f);
    float dsum = 0.f;
    AGG_BATCH8()
    float inv = 1.f / fmaxf(dsum, 1e-9f);
    float v0 = elu_f(acc.x * inv), v1 = elu_f(acc.y * inv);
    float v2 = elu_f(acc.z * inv), v3 = elu_f(acc.w * inv);
    size_t base = (size_t)h * N_NODES * (ND + NC) + (size_t)n * (ND + NC);
    *(float4*)(out + base + g * 4) = make_float4(v0, v1, v2, v3);
    float logit[NC];
    #pragma unroll
    for (int c = 0; c < NC; ++c) {
        int d0 = g * 4;
        float p = v0 * Wc[(d0 + 0) * NC + c] + v1 * Wc[(d0 + 1) * NC + c] +
                  v2 * Wc[(d0 + 2) * NC + c] + v3 * Wc[(d0 + 3) * NC + c];
        p += __shfl_xor(p, 1, 64);
        p += __shfl_xor(p, 2, 64);
        p += __shfl_xor(p, 4, 64);
        p += __shfl_xor(p, 8, 64);
        logit[c] = p + bc[c];
    }
    float m = logit[0];
    #pragma unroll
    for (int c = 1; c < NC; ++c) m = fmaxf(m, logit[c]);
    float ssum = 0.f;
    #pragma unroll
    for (int c = 0; c < NC; ++c) ssum += __expf(logit[c] - m);
    out[base + ND + g] = __expf(logit[g] - m) / ssum;
}

extern "C" void kernel_launch(void* const* d_in, const int* in_sizes, int n_in,
                              void* d_out, int out_size, void* d_ws, size_t ws_size,
                              hipStream_t stream) {
    const float* x   = (const float*)d_in[0];
    const int* src   = (const int*)d_in[1];
    const int* dst   = (const int*)d_in[2];
    const float* W0  = (const float*)d_in[3];
    const float* al0 = (const float*)d_in[4];
    const float* ar0 = (const float*)d_in[5];
    const float* W1  = (const float*)d_in[6];
    const float* al1 = (const float*)d_in[7];
    const float* ar1 = (const float*)d_in[8];
    const float* Wc  = (const float*)d_in[9];
    const float* bc  = (const float*)d_in[10];
    float* out = (float*)d_out;

    char* ws = (char*)d_ws;
    size_t off = 0;
    auto alloc = [&](size_t bytes) { void* p = ws + off; off = (off + bytes + 255) & ~(size_t)255; return p; };
    float*  feat   = (float*)alloc((size_t)N_NODES * NF * 4);    // 51.2 MB (f32 GEMM out, for el/er)
    ushort* featbf = (ushort*)alloc((size_t)N_NODES * NF * 2);   // 25.6 MB (bf16 GEMM out, for gather)
    ushort* xbf    = (ushort*)alloc((size_t)N_NODES * NF * 2);   // 25.6 MB
    ushort* hbuf   = (ushort*)alloc((size_t)N_NODES * NF * 2);   // 25.6 MB (layer0 out, bf16)
    ushort* Wt0    = (ushort*)alloc((size_t)256 * 256 * 2);
    ushort* Wt1    = (ushort*)alloc((size_t)256 * 256 * 2);
    float*  el     = (float*)alloc((size_t)N_NODES * NH * 4);
    float*  er     = (float*)alloc((size_t)N_NODES * NH * 4);
    int* counts    = (int*)alloc((size_t)N_NODES * 4);
    int* offs      = (int*)alloc((size_t)(N_NODES + 1) * 4);
    int* cursor    = (int*)alloc((size_t)N_NODES * 4);
    int* csrc      = (int*)alloc((size_t)N_EDGES * 4);
    int* bsums     = (int*)alloc(256 * 4);
    int* boffs     = (int*)alloc(256 * 4);

    const int EB = (N_EDGES + 255) / 256;          // 3125
    const int NB = (N_NODES + 255) / 256;          // 196
    const int GEMM_MB = (N_NODES + 127) / 128;     // 391
    const int C8 = (N_NODES * NF / 8 + 255) / 256;

    // ---- CSR build (stores src ids directly) ----
    hipMemsetAsync(counts, 0, (size_t)N_NODES * 4, stream);
    hist_kernel<<<EB, 256, 0, stream>>>(dst, counts);
    scan1_kernel<<<NB, 256, 0, stream>>>(counts, offs, bsums);
    scan2_kernel<<<1, 256, 0, stream>>>(bsums, boffs, NB);
    scan3_kernel<<<NB, 256, 0, stream>>>(offs, boffs, cursor);
    scatter_kernel<<<EB, 256, 0, stream>>>(src, dst, cursor, csrc);

    // ---- weight + input casts ----
    castWt_kernel<<<512, 256, 0, stream>>>(W0, W1, Wt0, Wt1);
    cast_bf16_kernel<<<C8, 256, 0, stream>>>(x, xbf, N_NODES * NF / 8);

    // ---- Layer 0 ----
    gemm_bf16<<<dim3(GEMM_MB, 2), 256, 0, stream>>>(xbf, Wt0, feat, featbf, N_NODES);
    eler_kernel<<<N_NODES, 256, 0, stream>>>(feat, al0, ar0, el, er);
    agg_l0_kernel<<<N_NODES / 4, 256, 0, stream>>>(featbf, csrc, offs, el, er, hbuf);

    // ---- Layer 1 ----
    gemm_bf16<<<dim3(GEMM_MB, 2), 256, 0, stream>>>(hbuf, Wt1, feat, featbf, N_NODES);
    eler_kernel<<<N_NODES, 256, 0, stream>>>(feat, al1, ar1, el, er);
    agg_final_kernel<<<N_NODES / 4, 256, 0, stream>>>(featbf, csrc, offs, el, er, Wc, bc, out);
}

// Round 4
// 379.965 us; speedup vs baseline: 2.6462x; 1.1104x over previous
//
#include <hip/hip_runtime.h>
#include <hip/hip_bf16.h>
#include <math.h>

#define N_NODES 50000
#define N_EDGES 800000
#define NH 4
#define ND 64
#define NF 256   // NH*ND = feature width everywhere (IN=256 too)
#define NC 16
#define NEG_SLOPE 0.2f

typedef __attribute__((ext_vector_type(8))) short bf16x8;
typedef __attribute__((ext_vector_type(4))) float f32x4;

__device__ __forceinline__ float elu_f(float x) {
    return x > 0.f ? x : (__expf(x) - 1.f);
}

__device__ __forceinline__ ushort bf16_rne(float f) {
    union { float f; unsigned u; } v; v.f = f;
    unsigned u = v.u;
    u += 0x7fffu + ((u >> 16) & 1u);   // round-to-nearest-even
    return (ushort)(u >> 16);
}

__device__ __forceinline__ float bf2f(ushort u) {
    return __uint_as_float(((unsigned)u) << 16);
}

// ---------------- cast x (f32) -> bf16 ----------------
__global__ __launch_bounds__(256) void cast_bf16_kernel(const float* __restrict__ in,
                                                        ushort* __restrict__ out, int n8) {
    int i = blockIdx.x * 256 + threadIdx.x;
    if (i >= n8) return;
    float4 a = *(const float4*)(in + i * 8);
    float4 b = *(const float4*)(in + i * 8 + 4);
    ushort o[8] = {bf16_rne(a.x), bf16_rne(a.y), bf16_rne(a.z), bf16_rne(a.w),
                   bf16_rne(b.x), bf16_rne(b.y), bf16_rne(b.z), bf16_rne(b.w)};
    *(bf16x8*)(out + i * 8) = *(bf16x8*)o;
}

// ---- transpose+cast W[k][n] f32 -> Wt[n][k] bf16, two weights in one launch ----
__global__ __launch_bounds__(256) void castWt_kernel(const float* __restrict__ W0,
                                                     const float* __restrict__ W1,
                                                     ushort* __restrict__ Wt0,
                                                     ushort* __restrict__ Wt1) {
    const float* W = (blockIdx.x < 256) ? W0 : W1;
    ushort* Wt = (blockIdx.x < 256) ? Wt0 : Wt1;
    int n = blockIdx.x & 255;
    int k = threadIdx.x;
    Wt[n * 256 + k] = bf16_rne(W[k * 256 + n]);
}

// ---------------- GEMM: Cbf[M,256]bf16 = A[M,256]bf16 @ Bt[n][k]bf16 ----------------
// 128x128 tile, BK=64, 256 threads (4 waves 2x2), 16x16x32 MFMA, XOR-swizzled LDS.
// Fused epilogue: el/er = dot(feat_row, al/ar) per head — each wave's 64 output
// cols are exactly one head, so a 16-lane shfl reduce completes the dot. No atomics.
__global__ __launch_bounds__(256) void gemm_bf16(const ushort* __restrict__ A,
                                                 const ushort* __restrict__ Bt,
                                                 ushort* __restrict__ Cbf,
                                                 const float* __restrict__ al,
                                                 const float* __restrict__ ar,
                                                 float* __restrict__ el,
                                                 float* __restrict__ er, int M) {
    __shared__ __align__(16) ushort As[128 * 64];   // [row][k], 16B blocks XOR-swizzled
    __shared__ __align__(16) ushort Bs[128 * 64];   // [col][k], same
    const int t = threadIdx.x;
    const int l = t & 63;
    const int w = t >> 6;
    const int wm = (w >> 1) * 64, wn = (w & 1) * 64;
    const int m0 = blockIdx.x * 128, n0 = blockIdx.y * 128;
    const int lr = l & 15, lk = l >> 4;

    f32x4 acc[4][4] = {};
    const int sr = t >> 3;            // staging row-in-issue 0..31
    const int sc = t & 7;             // global 16B-block col
    const int scw = sc ^ (sr & 7);    // swizzled LDS block

    for (int k0 = 0; k0 < 256; k0 += 64) {
        #pragma unroll
        for (int q = 0; q < 4; ++q) {
            int row = q * 32 + sr;
            int ga = min(m0 + row, M - 1);
            bf16x8 va = *(const bf16x8*)(A + (size_t)ga * 256 + k0 + sc * 8);
            *(bf16x8*)(&As[row * 64 + scw * 8]) = va;
            bf16x8 vb = *(const bf16x8*)(Bt + (size_t)(n0 + row) * 256 + k0 + sc * 8);
            *(bf16x8*)(&Bs[row * 64 + scw * 8]) = vb;
        }
        __syncthreads();
        #pragma unroll
        for (int kk = 0; kk < 2; ++kk) {
            bf16x8 af[4], bfr[4];
            #pragma unroll
            for (int mi = 0; mi < 4; ++mi) {
                int row = wm + mi * 16 + lr;
                int kb = kk * 4 + lk;
                af[mi] = *(const bf16x8*)(&As[row * 64 + (kb ^ (row & 7)) * 8]);
            }
            #pragma unroll
            for (int ni = 0; ni < 4; ++ni) {
                int col = wn + ni * 16 + lr;
                int kb = kk * 4 + lk;
                bfr[ni] = *(const bf16x8*)(&Bs[col * 64 + (kb ^ (col & 7)) * 8]);
            }
            #pragma unroll
            for (int mi = 0; mi < 4; ++mi)
                #pragma unroll
                for (int ni = 0; ni < 4; ++ni)
                    acc[mi][ni] = __builtin_amdgcn_mfma_f32_16x16x32_bf16(af[mi], bfr[ni], acc[mi][ni], 0, 0, 0);
        }
        __syncthreads();
    }
    // this wave's head and its al/ar slice (d = ni*16 + lr)
    const int h = (n0 + wn) >> 6;
    float alv[4], arv[4];
    #pragma unroll
    for (int ni = 0; ni < 4; ++ni) {
        alv[ni] = al[h * ND + ni * 16 + lr];
        arv[ni] = ar[h * ND + ni * 16 + lr];
    }
    // C/D layout: col = lane&15, row = (lane>>4)*4 + reg  [m89-verified]
    #pragma unroll
    for (int mi = 0; mi < 4; ++mi) {
        #pragma unroll
        for (int j = 0; j < 4; ++j) {
            int row = m0 + wm + mi * 16 + lk * 4 + j;
            float pe = 0.f, pr = 0.f;
            #pragma unroll
            for (int ni = 0; ni < 4; ++ni) {
                float v = acc[mi][ni][j];
                pe += v * alv[ni];
                pr += v * arv[ni];
                if (row < M)
                    Cbf[(size_t)row * 256 + n0 + wn + ni * 16 + lr] = bf16_rne(v);
            }
            #pragma unroll
            for (int m = 1; m <= 8; m <<= 1) {
                pe += __shfl_xor(pe, m, 64);
                pr += __shfl_xor(pr, m, 64);
            }
            if (lr == 0 && row < M) {
                el[row * 4 + h] = pe;
                er[row * 4 + h] = pr;
            }
        }
    }
}

// -------- CSR build --------
__global__ __launch_bounds__(256) void hist_kernel(const int* __restrict__ dst, int* __restrict__ count) {
    int e = blockIdx.x * 256 + threadIdx.x;
    if (e < N_EDGES) atomicAdd(&count[dst[e]], 1);
}

__global__ __launch_bounds__(256) void scan1_kernel(const int* __restrict__ counts,
                                                    int* __restrict__ offs,
                                                    int* __restrict__ bsums) {
    __shared__ int sh[256];
    int tid = threadIdx.x;
    int i = blockIdx.x * 256 + tid;
    int v = (i < N_NODES) ? counts[i] : 0;
    sh[tid] = v;
    __syncthreads();
    #pragma unroll
    for (int ofs = 1; ofs < 256; ofs <<= 1) {
        int t = (tid >= ofs) ? sh[tid - ofs] : 0;
        __syncthreads();
        sh[tid] += t;
        __syncthreads();
    }
    if (i < N_NODES) offs[i] = sh[tid] - v;
    if (tid == 255) bsums[blockIdx.x] = sh[255];
}

__global__ __launch_bounds__(256) void scan2_kernel(const int* __restrict__ bsums,
                                                    int* __restrict__ boffs, int nb) {
    __shared__ int sh[256];
    int tid = threadIdx.x;
    int v = (tid < nb) ? bsums[tid] : 0;
    sh[tid] = v;
    __syncthreads();
    #pragma unroll
    for (int ofs = 1; ofs < 256; ofs <<= 1) {
        int t = (tid >= ofs) ? sh[tid - ofs] : 0;
        __syncthreads();
        sh[tid] += t;
        __syncthreads();
    }
    if (tid < nb) boffs[tid] = sh[tid] - v;
}

// scan3: finalize offs AND init cursor (absolute write positions)
__global__ __launch_bounds__(256) void scan3_kernel(int* __restrict__ offs,
                                                    const int* __restrict__ boffs,
                                                    int* __restrict__ cursor) {
    int i = blockIdx.x * 256 + threadIdx.x;
    if (i < N_NODES) {
        int v = offs[i] + boffs[i >> 8];
        offs[i] = v;
        cursor[i] = v;
    }
    if (i == 0) offs[N_NODES] = N_EDGES;
}

// scatter: store src AND dst node ids per slot
__global__ __launch_bounds__(256) void scatter_kernel(const int* __restrict__ src,
                                                      const int* __restrict__ dst,
                                                      int* __restrict__ cursor,
                                                      int* __restrict__ csrc,
                                                      int* __restrict__ cdst) {
    int e = blockIdx.x * 256 + threadIdx.x;
    if (e >= N_EDGES) return;
    int d = dst[e];
    int p = atomicAdd(&cursor[d], 1);
    csrc[p] = src[e];
    cdst[p] = d;
}

// -------- per-slot attention weights: w[i][h] = exp(leaky(el[src]+er[dst])) --------
// streaming; el/er are 800KB tables -> L2-resident gathers.
__global__ __launch_bounds__(256) void edge_w_kernel(const int* __restrict__ csrc,
                                                     const int* __restrict__ cdst,
                                                     const float* __restrict__ el,
                                                     const float* __restrict__ er,
                                                     float* __restrict__ w) {
    int i = blockIdx.x * 256 + threadIdx.x;
    if (i >= N_EDGES) return;
    int s = csrc[i], d = cdst[i];
    float4 lv = *(const float4*)(el + s * 4);
    float4 rv = *(const float4*)(er + d * 4);
    float lvv[4] = {lv.x, lv.y, lv.z, lv.w};
    float rvv[4] = {rv.x, rv.y, rv.z, rv.w};
    float o[4];
    #pragma unroll
    for (int hh = 0; hh < 4; ++hh) {
        float v = lvv[hh] + rvv[hh];
        v = v > 0.f ? v : NEG_SLOPE * v;
        o[hh] = __expf(v);
    }
    *(float4*)(w + (size_t)i * 4) = make_float4(o[0], o[1], o[2], o[3]);
}

// -------- aggregation: contiguous csrc/w streams, only feat is scattered; 16-deep MLP --------
// one wave per node; lane = 4-bf16 chunk (8B) of the 256 features.
#define AGG_BATCH16()                                                            \
    for (int i = s0; i < s1; i += 16) {                                          \
        int sid[16]; float wv[16]; ushort4 fr[16];                               \
        _Pragma("unroll")                                                        \
        for (int u = 0; u < 16; ++u) {                                           \
            int idx = (i + u < s1) ? i + u : s1 - 1;                             \
            sid[u] = csrc[idx];                                                  \
            wv[u] = (i + u < s1) ? w[(size_t)idx * 4 + h] : 0.f;                 \
        }                                                                        \
        _Pragma("unroll")                                                        \
        for (int u = 0; u < 16; ++u)                                             \
            fr[u] = *(const ushort4*)(featbf + (size_t)sid[u] * NF + lane * 4);  \
        _Pragma("unroll")                                                        \
        for (int u = 0; u < 16; ++u) {                                           \
            dsum += wv[u];                                                       \
            acc.x += wv[u] * bf2f(fr[u].x);                                      \
            acc.y += wv[u] * bf2f(fr[u].y);                                      \
            acc.z += wv[u] * bf2f(fr[u].z);                                      \
            acc.w += wv[u] * bf2f(fr[u].w);                                      \
        }                                                                        \
    }

__global__ __launch_bounds__(256) void agg_l0_kernel(const ushort* __restrict__ featbf,
                                                     const int* __restrict__ csrc,
                                                     const int* __restrict__ offs,
                                                     const float* __restrict__ w,
                                                     ushort* __restrict__ out_bf) {
    int n = blockIdx.x * 4 + (threadIdx.x >> 6);
    int lane = threadIdx.x & 63;
    int h = lane >> 4;
    int s0 = offs[n], s1 = offs[n + 1];
    float4 acc = make_float4(0.f, 0.f, 0.f, 0.f);
    float dsum = 0.f;
    AGG_BATCH16()
    float inv = 1.f / fmaxf(dsum, 1e-9f);
    ushort o[4] = {bf16_rne(elu_f(acc.x * inv)), bf16_rne(elu_f(acc.y * inv)),
                   bf16_rne(elu_f(acc.z * inv)), bf16_rne(elu_f(acc.w * inv))};
    *(ushort4*)(out_bf + (size_t)n * NF + lane * 4) = *(ushort4*)o;
}

// -------- final: aggregation + elu + heads write + cluster softmax --------
__global__ __launch_bounds__(256) void agg_final_kernel(const ushort* __restrict__ featbf,
                                                        const int* __restrict__ csrc,
                                                        const int* __restrict__ offs,
                                                        const float* __restrict__ w,
                                                        const float* __restrict__ Wc,
                                                        const float* __restrict__ bc,
                                                        float* __restrict__ out) {
    int n = blockIdx.x * 4 + (threadIdx.x >> 6);
    int lane = threadIdx.x & 63;
    int h = lane >> 4;
    int g = lane & 15;
    int s0 = offs[n], s1 = offs[n + 1];
    float4 acc = make_float4(0.f, 0.f, 0.f, 0.f);
    float dsum = 0.f;
    AGG_BATCH16()
    float inv = 1.f / fmaxf(dsum, 1e-9f);
    float v0 = elu_f(acc.x * inv), v1 = elu_f(acc.y * inv);
    float v2 = elu_f(acc.z * inv), v3 = elu_f(acc.w * inv);
    size_t base = (size_t)h * N_NODES * (ND + NC) + (size_t)n * (ND + NC);
    *(float4*)(out + base + g * 4) = make_float4(v0, v1, v2, v3);
    float logit[NC];
    #pragma unroll
    for (int c = 0; c < NC; ++c) {
        int d0 = g * 4;
        float p = v0 * Wc[(d0 + 0) * NC + c] + v1 * Wc[(d0 + 1) * NC + c] +
                  v2 * Wc[(d0 + 2) * NC + c] + v3 * Wc[(d0 + 3) * NC + c];
        p += __shfl_xor(p, 1, 64);
        p += __shfl_xor(p, 2, 64);
        p += __shfl_xor(p, 4, 64);
        p += __shfl_xor(p, 8, 64);
        logit[c] = p + bc[c];
    }
    float m = logit[0];
    #pragma unroll
    for (int c = 1; c < NC; ++c) m = fmaxf(m, logit[c]);
    float ssum = 0.f;
    #pragma unroll
    for (int c = 0; c < NC; ++c) ssum += __expf(logit[c] - m);
    out[base + ND + g] = __expf(logit[g] - m) / ssum;
}

extern "C" void kernel_launch(void* const* d_in, const int* in_sizes, int n_in,
                              void* d_out, int out_size, void* d_ws, size_t ws_size,
                              hipStream_t stream) {
    const float* x   = (const float*)d_in[0];
    const int* src   = (const int*)d_in[1];
    const int* dst   = (const int*)d_in[2];
    const float* W0  = (const float*)d_in[3];
    const float* al0 = (const float*)d_in[4];
    const float* ar0 = (const float*)d_in[5];
    const float* W1  = (const float*)d_in[6];
    const float* al1 = (const float*)d_in[7];
    const float* ar1 = (const float*)d_in[8];
    const float* Wc  = (const float*)d_in[9];
    const float* bc  = (const float*)d_in[10];
    float* out = (float*)d_out;

    char* ws = (char*)d_ws;
    size_t off = 0;
    auto alloc = [&](size_t bytes) { void* p = ws + off; off = (off + bytes + 255) & ~(size_t)255; return p; };
    ushort* featbf = (ushort*)alloc((size_t)N_NODES * NF * 2);   // 25.6 MB (GEMM out, bf16)
    ushort* xbf    = (ushort*)alloc((size_t)N_NODES * NF * 2);   // 25.6 MB
    ushort* hbuf   = (ushort*)alloc((size_t)N_NODES * NF * 2);   // 25.6 MB (layer0 out, bf16)
    ushort* Wt0    = (ushort*)alloc((size_t)256 * 256 * 2);
    ushort* Wt1    = (ushort*)alloc((size_t)256 * 256 * 2);
    float*  el     = (float*)alloc((size_t)N_NODES * NH * 4);
    float*  er     = (float*)alloc((size_t)N_NODES * NH * 4);
    float*  wbuf   = (float*)alloc((size_t)N_EDGES * NH * 4);    // 12.8 MB per-slot weights
    int* counts    = (int*)alloc((size_t)N_NODES * 4);
    int* offs      = (int*)alloc((size_t)(N_NODES + 1) * 4);
    int* cursor    = (int*)alloc((size_t)N_NODES * 4);
    int* csrc      = (int*)alloc((size_t)N_EDGES * 4);
    int* cdst      = (int*)alloc((size_t)N_EDGES * 4);
    int* bsums     = (int*)alloc(256 * 4);
    int* boffs     = (int*)alloc(256 * 4);

    const int EB = (N_EDGES + 255) / 256;          // 3125
    const int NB = (N_NODES + 255) / 256;          // 196
    const int GEMM_MB = (N_NODES + 127) / 128;     // 391
    const int C8 = (N_NODES * NF / 8 + 255) / 256;

    // ---- CSR build (stores src+dst ids per slot) ----
    hipMemsetAsync(counts, 0, (size_t)N_NODES * 4, stream);
    hist_kernel<<<EB, 256, 0, stream>>>(dst, counts);
    scan1_kernel<<<NB, 256, 0, stream>>>(counts, offs, bsums);
    scan2_kernel<<<1, 256, 0, stream>>>(bsums, boffs, NB);
    scan3_kernel<<<NB, 256, 0, stream>>>(offs, boffs, cursor);
    scatter_kernel<<<EB, 256, 0, stream>>>(src, dst, cursor, csrc, cdst);

    // ---- weight + input casts ----
    castWt_kernel<<<512, 256, 0, stream>>>(W0, W1, Wt0, Wt1);
    cast_bf16_kernel<<<C8, 256, 0, stream>>>(x, xbf, N_NODES * NF / 8);

    // ---- Layer 0 ----
    gemm_bf16<<<dim3(GEMM_MB, 2), 256, 0, stream>>>(xbf, Wt0, featbf, al0, ar0, el, er, N_NODES);
    edge_w_kernel<<<EB, 256, 0, stream>>>(csrc, cdst, el, er, wbuf);
    agg_l0_kernel<<<N_NODES / 4, 256, 0, stream>>>(featbf, csrc, offs, wbuf, hbuf);

    // ---- Layer 1 ----
    gemm_bf16<<<dim3(GEMM_MB, 2), 256, 0, stream>>>(hbuf, Wt1, featbf, al1, ar1, el, er, N_NODES);
    edge_w_kernel<<<EB, 256, 0, stream>>>(csrc, cdst, el, er, wbuf);
    agg_final_kernel<<<N_NODES / 4, 256, 0, stream>>>(featbf, csrc, offs, wbuf, Wc, bc, out);
}